// Round 1
// baseline (542.839 us; speedup 1.0000x reference)
//
#include <hip/hip_runtime.h>

#define B_   8
#define SQ_  2048
#define SK_  2048
#define D_   128
#define KSPLIT_ 4
#define KRANGE_ (SK_ / KSPLIT_)   // 512 k rows per split
#define NSTEP_  (KRANGE_ / 16)    // 32 steps of 16 k
#define BSQ_ (B_ * SQ_)           // 16384 rows

typedef float  f32x4 __attribute__((ext_vector_type(4)));
typedef short  s16x8 __attribute__((ext_vector_type(8)));
typedef short  s16x4 __attribute__((ext_vector_type(4)));
typedef __bf16 b16x8 __attribute__((ext_vector_type(8)));

__device__ __forceinline__ f32x4 mfma_k32(s16x8 a, s16x8 b, f32x4 c) {
    return __builtin_amdgcn_mfma_f32_16x16x32_bf16(
        __builtin_bit_cast(b16x8, a), __builtin_bit_cast(b16x8, b), c, 0, 0, 0);
}

#if __has_builtin(__builtin_amdgcn_mfma_f32_16x16x16bf16_1k)
__device__ __forceinline__ f32x4 mfma_k16(s16x4 a, s16x4 b, f32x4 c) {
    return __builtin_amdgcn_mfma_f32_16x16x16bf16_1k(a, b, c, 0, 0, 0);
}
#else
__device__ __forceinline__ f32x4 mfma_k16(s16x4 a, s16x4 b, f32x4 c) {
    f32x4 d;
    asm("v_mfma_f32_16x16x16_bf16 %0, %1, %2, %3" : "=v"(d) : "v"(a), "v"(b), "v"(c));
    return d;
}
#endif

// truncate-to-bf16 pack of two floats (a -> low u16, b -> high u16)
__device__ __forceinline__ unsigned int bfpack(float a, float b) {
    return (__float_as_uint(a) >> 16) | (__float_as_uint(b) & 0xFFFF0000u);
}

// hi/lo split: hi = trunc-bf16(v); lo = trunc-bf16(v - hi).
__device__ __forceinline__ void split4(const float4 v, uint2& hi, uint2& lo) {
    float hx = __uint_as_float(__float_as_uint(v.x) & 0xFFFF0000u);
    float hy = __uint_as_float(__float_as_uint(v.y) & 0xFFFF0000u);
    float hz = __uint_as_float(__float_as_uint(v.z) & 0xFFFF0000u);
    float hw = __uint_as_float(__float_as_uint(v.w) & 0xFFFF0000u);
    hi.x = bfpack(v.x, v.y); hi.y = bfpack(v.z, v.w);
    lo.x = bfpack(v.x - hx, v.y - hy); lo.y = bfpack(v.z - hz, v.w - hw);
}

union U8 { unsigned int u[4]; s16x8 v; };
union U4 { unsigned int u[2]; s16x4 v; };

// One 16k x 16q S^T subtile: A = K rows (hi/lo split on the fly),
// B = qw fragments (pre-split, resident in registers).
// Output lane layout: col = l15 = q, row = quad*4 + r = k. 3-term hi/lo product.
// MUST be called with identical inputs/order in k_stats and k_fused (l-consistency).
__device__ __forceinline__ f32x4 qk_tile(const float* __restrict__ kr,
                                         const s16x8* q_hi, const s16x8* q_lo,
                                         int quad) {
    f32x4 acc = (f32x4){0.f, 0.f, 0.f, 0.f};
    #pragma unroll
    for (int dc = 0; dc < 4; ++dc) {
        const float* p = kr + dc * 32 + quad * 8;
        float4 v0 = *(const float4*)p;
        float4 v1 = *(const float4*)(p + 4);
        uint2 h0, l0, h1, l1;
        split4(v0, h0, l0); split4(v1, h1, l1);
        U8 H, L;
        H.u[0] = h0.x; H.u[1] = h0.y; H.u[2] = h1.x; H.u[3] = h1.y;
        L.u[0] = l0.x; L.u[1] = l0.y; L.u[2] = l1.x; L.u[3] = l1.y;
        acc = mfma_k32(H.v, q_hi[dc], acc);   // K_hi * qw_hi
        acc = mfma_k32(L.v, q_hi[dc], acc);   // K_lo * qw_hi
        acc = mfma_k32(H.v, q_lo[dc], acc);   // K_hi * qw_lo
    }
    return acc;
}

// ---------------------------------------------------------------------------
// K1: qw = Q @ W, output packed hi/lo bf16 rows: [row][128 hi u16 | 128 lo u16]
// (512 B/row, aliases the `out` region exactly like the old fp32 qw did).
// ---------------------------------------------------------------------------
__global__ __launch_bounds__(256) void k1_qw(const float* __restrict__ q,
                                             const float* __restrict__ w,
                                             unsigned int* __restrict__ qwp) {
    __shared__ float Ws[D_ * D_];
    const int tid = threadIdx.x;
    const int rowbase = blockIdx.x * 64;
    #pragma unroll
    for (int t = 0; t < 16; ++t) {
        int i4 = t * 256 + tid;
        ((float4*)Ws)[i4] = ((const float4*)w)[i4];
    }
    __syncthreads();
    const int mg = tid >> 4, cg = tid & 15;
    const int c0 = cg * 8;
    const float* qrow[4];
    #pragma unroll
    for (int i = 0; i < 4; ++i)
        qrow[i] = q + (size_t)(rowbase + mg * 4 + i) * D_;
    float acc[4][8];
    #pragma unroll
    for (int i = 0; i < 4; ++i)
        #pragma unroll
        for (int j = 0; j < 8; ++j) acc[i][j] = 0.0f;
    for (int d0 = 0; d0 < D_; d0 += 16) {
        float qr[4][16];
        #pragma unroll
        for (int i = 0; i < 4; ++i)
            #pragma unroll
            for (int c4 = 0; c4 < 4; ++c4)
                *(float4*)&qr[i][c4 * 4] = *(const float4*)(qrow[i] + d0 + c4 * 4);
        #pragma unroll
        for (int dd = 0; dd < 16; ++dd) {
            const int d = d0 + dd;
            float4 w0 = *(const float4*)&Ws[d * D_ + c0];
            float4 w1 = *(const float4*)&Ws[d * D_ + c0 + 4];
            #pragma unroll
            for (int i = 0; i < 4; ++i) {
                float a = qr[i][dd];
                acc[i][0] += a * w0.x; acc[i][1] += a * w0.y;
                acc[i][2] += a * w0.z; acc[i][3] += a * w0.w;
                acc[i][4] += a * w1.x; acc[i][5] += a * w1.y;
                acc[i][6] += a * w1.z; acc[i][7] += a * w1.w;
            }
        }
    }
    #pragma unroll
    for (int i = 0; i < 4; ++i) {
        float4 v0 = make_float4(acc[i][0], acc[i][1], acc[i][2], acc[i][3]);
        float4 v1 = make_float4(acc[i][4], acc[i][5], acc[i][6], acc[i][7]);
        uint2 h0, l0, h1, l1;
        split4(v0, h0, l0); split4(v1, h1, l1);
        unsigned int* dst = qwp + (size_t)(rowbase + mg * 4 + i) * 128;
        *(uint4*)(dst + cg * 4)      = make_uint4(h0.x, h0.y, h1.x, h1.y);
        *(uint4*)(dst + 64 + cg * 4) = make_uint4(l0.x, l0.y, l1.x, l1.y);
    }
}

// ---------------------------------------------------------------------------
// K_stats: per-row (max, sumexp) partials by RECOMPUTING S^T on the fly.
// wave = 16 q-rows x 512 k (one of 4 k-splits). No LDS, no barriers.
// wid layout: [b:3][ks:2][qb:7]  -> a block's 4 waves share one k-split
// (K rows L1/L2-shared), XCD-swizzle puts one batch per XCD.
// ---------------------------------------------------------------------------
__global__ __launch_bounds__(256, 4) void k_stats(
        const unsigned short* __restrict__ qwp, const float* __restrict__ key,
        float* __restrict__ mp, float* __restrict__ lp) {
    const int blk  = ((int)blockIdx.x & 7) * 128 + ((int)blockIdx.x >> 3);
    const int wid  = blk * 4 + (threadIdx.x >> 6);
    const int lane = threadIdx.x & 63;
    const int quad = lane >> 4, l15 = lane & 15;
    const int qb = wid & 127;
    const int ks = (wid >> 7) & 3;
    const int b  = wid >> 9;

    const unsigned short* qrow = qwp + ((size_t)b * SQ_ + qb * 16 + l15) * 256;
    s16x8 q_hi[4], q_lo[4];
    #pragma unroll
    for (int dc = 0; dc < 4; ++dc) {
        q_hi[dc] = *(const s16x8*)(qrow + dc * 32 + quad * 8);
        q_lo[dc] = *(const s16x8*)(qrow + 128 + dc * 32 + quad * 8);
    }

    const float* Kb = key + ((size_t)b * SK_ + ks * KRANGE_) * D_;
    float m_run = -3.0e38f, l_run = 0.f;
    for (int st = 0; st < NSTEP_; ++st) {
        const float* kr = Kb + (size_t)(st * 16 + l15) * D_;
        f32x4 acc = qk_tile(kr, q_hi, q_lo, quad);
        float t = fmaxf(fmaxf(acc[0], acc[1]), fmaxf(acc[2], acc[3]));
        float mn = fmaxf(m_run, t);
        l_run = l_run * __expf(m_run - mn)
              + __expf(acc[0] - mn) + __expf(acc[1] - mn)
              + __expf(acc[2] - mn) + __expf(acc[3] - mn);
        m_run = mn;
    }
    // combine the 4 quads (lane, lane^16, lane^32, lane^48)
    #pragma unroll
    for (int off = 16; off <= 32; off <<= 1) {
        float om = __shfl_xor(m_run, off, 64);
        float ol = __shfl_xor(l_run, off, 64);
        float mn = fmaxf(m_run, om);
        l_run = l_run * __expf(m_run - mn) + ol * __expf(om - mn);
        m_run = mn;
    }
    if (lane < 16) {
        size_t row = (size_t)b * SQ_ + qb * 16 + l15;
        mp[(size_t)ks * BSQ_ + row] = m_run;
        lp[(size_t)ks * BSQ_ + row] = l_run;
    }
}

// ---------------------------------------------------------------------------
// K_fused: recompute S^T (bit-identical to k_stats), normalize, write weight
// ONCE (float4/lane: the 4 acc regs are 4 consecutive k), and do PV with
// mfma 16x16x16 whose A-fragment layout (q=l15, k=quad*4+r) EXACTLY matches
// the S^T output registers -> P never leaves registers. LDS only for the
// final 4-way k-split O reduction.
// block = 512 thr = 8 waves = 2 q-groups x 4 k-splits -> 32 q rows/block.
// ---------------------------------------------------------------------------
__global__ __launch_bounds__(512, 4) void k_fused(
        const unsigned short* qwp, const float* __restrict__ key,
        const float* __restrict__ val, float* out, float* __restrict__ wgt,
        const float* __restrict__ mp, const float* __restrict__ lp) {
    __shared__ float Ot[32][132];
    const int tid  = threadIdx.x;
    const int blk  = ((int)blockIdx.x & 7) * 64 + ((int)blockIdx.x >> 3);
    const int wv   = tid >> 6;
    const int qg   = wv >> 2;        // 0,1: q-group within block
    const int ks   = wv & 3;         // k-split
    const int lane = tid & 63, quad = lane >> 4, l15 = lane & 15;
    const int b  = blk >> 6;
    const int qb = (blk & 63) * 2 + qg;   // 16-row q group index (0..127)

    for (int i = tid; i < 32 * 132; i += 512) ((float*)Ot)[i] = 0.f;
    __syncthreads();

    const unsigned short* qrow = qwp + ((size_t)b * SQ_ + qb * 16 + l15) * 256;
    s16x8 q_hi[4], q_lo[4];
    #pragma unroll
    for (int dc = 0; dc < 4; ++dc) {
        q_hi[dc] = *(const s16x8*)(qrow + dc * 32 + quad * 8);
        q_lo[dc] = *(const s16x8*)(qrow + 128 + dc * 32 + quad * 8);
    }

    const size_t row = (size_t)b * SQ_ + qb * 16 + l15;
    float mf = -3.0e38f, lf = 0.f;
    #pragma unroll
    for (int s = 0; s < KSPLIT_; ++s) {
        float ms = mp[(size_t)s * BSQ_ + row];
        float ls = lp[(size_t)s * BSQ_ + row];
        float mn = fmaxf(mf, ms);
        lf = lf * __expf(mf - mn) + ls * __expf(ms - mn);
        mf = mn;
    }
    const float linv = 1.0f / lf;

    const float* Kb = key + ((size_t)b * SK_ + ks * KRANGE_) * D_;
    const float* Vb = val + ((size_t)b * SK_ + ks * KRANGE_) * D_;
    float* Wp = wgt + row * SK_ + ks * KRANGE_ + quad * 4;

    f32x4 acc_o[8];
    #pragma unroll
    for (int i = 0; i < 8; ++i) acc_o[i] = (f32x4){0.f, 0.f, 0.f, 0.f};

    for (int st = 0; st < NSTEP_; ++st) {
        const float* kr = Kb + (size_t)(st * 16 + l15) * D_;
        f32x4 s4 = qk_tile(kr, q_hi, q_lo, quad);    // identical to k_stats
        f32x4 p;
        #pragma unroll
        for (int r = 0; r < 4; ++r) p[r] = __expf(s4[r] - mf) * linv;
        *(float4*)(Wp + st * 16) = make_float4(p[0], p[1], p[2], p[3]);
        U4 A; A.u[0] = bfpack(p[0], p[1]); A.u[1] = bfpack(p[2], p[3]);
        const float* vr = Vb + (size_t)(st * 16 + quad * 4) * D_ + l15;
        #pragma unroll
        for (int vt = 0; vt < 8; ++vt) {
            const float* vc = vr + vt * 16;
            U4 Bv;
            Bv.u[0] = bfpack(vc[0],        vc[D_]);
            Bv.u[1] = bfpack(vc[2 * D_],   vc[3 * D_]);
            acc_o[vt] = mfma_k16(A.v, Bv.v, acc_o[vt]);
        }
    }

    // 4-way k-split reduction of O in LDS (one-time)
    #pragma unroll
    for (int vt = 0; vt < 8; ++vt)
        #pragma unroll
        for (int r = 0; r < 4; ++r)
            atomicAdd(&Ot[qg * 16 + quad * 4 + r][vt * 16 + l15], acc_o[vt][r]);
    __syncthreads();

    float* ob = out + ((size_t)b * SQ_ + (size_t)(blk & 63) * 32) * D_;
    for (int i = tid; i < 32 * 32; i += 512) {
        int r = i >> 5, c4 = i & 31;
        *(float4*)(ob + (size_t)r * D_ + c4 * 4) = *(const float4*)&Ot[r][c4 * 4];
    }
}

extern "C" void kernel_launch(void* const* d_in, const int* in_sizes, int n_in,
                              void* d_out, int out_size, void* d_ws, size_t ws_size,
                              hipStream_t stream) {
    const float* q = (const float*)d_in[0];
    const float* k = (const float*)d_in[1];
    const float* v = (const float*)d_in[2];
    const float* w = (const float*)d_in[3];
    float* out    = (float*)d_out;
    float* weight = out + (size_t)BSQ_ * D_;
    unsigned int* qwp = (unsigned int*)out;     // packed hi/lo bf16 qw, aliases out
    float* mp = (float*)d_ws;                   // [KSPLIT][B*SQ] partial max
    float* lp = mp + (size_t)KSPLIT_ * BSQ_;    // [KSPLIT][B*SQ] partial sumexp

    k1_qw  <<<BSQ_ / 64, 256, 0, stream>>>(q, w, qwp);
    k_stats<<<BSQ_ / 16, 256, 0, stream>>>((const unsigned short*)qwp, k, mp, lp);
    k_fused<<<BSQ_ / 32, 512, 0, stream>>>((const unsigned short*)qwp, k, v, out,
                                           weight, mp, lp);
}

// Round 2
// 433.937 us; speedup vs baseline: 1.2510x; 1.2510x over previous
//
#include <hip/hip_runtime.h>

#define B_   8
#define SQ_  2048
#define SK_  2048
#define D_   128
#define KSPLIT_ 4
#define KRANGE_ (SK_ / KSPLIT_)   // 512 k rows per split
#define NSTEP_  (KRANGE_ / 16)    // 32 steps of 16 k
#define BSQ_ (B_ * SQ_)           // 16384 rows

typedef float  f32x4 __attribute__((ext_vector_type(4)));
typedef short  s16x8 __attribute__((ext_vector_type(8)));
typedef short  s16x4 __attribute__((ext_vector_type(4)));
typedef __bf16 b16x8 __attribute__((ext_vector_type(8)));

__device__ __forceinline__ f32x4 mfma_k32(s16x8 a, s16x8 b, f32x4 c) {
    return __builtin_amdgcn_mfma_f32_16x16x32_bf16(
        __builtin_bit_cast(b16x8, a), __builtin_bit_cast(b16x8, b), c, 0, 0, 0);
}

#if __has_builtin(__builtin_amdgcn_mfma_f32_16x16x16bf16_1k)
__device__ __forceinline__ f32x4 mfma_k16(s16x4 a, s16x4 b, f32x4 c) {
    return __builtin_amdgcn_mfma_f32_16x16x16bf16_1k(a, b, c, 0, 0, 0);
}
#else
__device__ __forceinline__ f32x4 mfma_k16(s16x4 a, s16x4 b, f32x4 c) {
    f32x4 d;
    asm("v_mfma_f32_16x16x16_bf16 %0, %1, %2, %3" : "=v"(d) : "v"(a), "v"(b), "v"(c));
    return d;
}
#endif

// truncate-to-bf16 pack of two floats (a -> low u16, b -> high u16)
__device__ __forceinline__ unsigned int bfpack(float a, float b) {
    return (__float_as_uint(a) >> 16) | (__float_as_uint(b) & 0xFFFF0000u);
}

// hi/lo split: hi = trunc-bf16(v); lo = trunc-bf16(v - hi).
__device__ __forceinline__ void split4(const float4 v, uint2& hi, uint2& lo) {
    float hx = __uint_as_float(__float_as_uint(v.x) & 0xFFFF0000u);
    float hy = __uint_as_float(__float_as_uint(v.y) & 0xFFFF0000u);
    float hz = __uint_as_float(__float_as_uint(v.z) & 0xFFFF0000u);
    float hw = __uint_as_float(__float_as_uint(v.w) & 0xFFFF0000u);
    hi.x = bfpack(v.x, v.y); hi.y = bfpack(v.z, v.w);
    lo.x = bfpack(v.x - hx, v.y - hy); lo.y = bfpack(v.z - hz, v.w - hw);
}

union U4 { unsigned int u[2]; s16x4 v; };

// One 16k x 16q S^T subtile from PRE-SPLIT K rows (hi|lo packed, 256 u16/row)
// and pre-split qw fragments in registers. Three independent accumulator
// chains (hh, lh, hl) for MFMA ILP; caller combines as (hh+lh)+hl.
// MUST be byte-identical between k_stats and k_fused (l-consistency).
__device__ __forceinline__ void qk3(const unsigned short* __restrict__ kr,
                                    const s16x8* q_hi, const s16x8* q_lo,
                                    int quad, f32x4& hh, f32x4& lh, f32x4& hl) {
    #pragma unroll
    for (int dc = 0; dc < 4; ++dc) {
        s16x8 H = *(const s16x8*)(kr + dc * 32 + quad * 8);
        s16x8 L = *(const s16x8*)(kr + 128 + dc * 32 + quad * 8);
        hh = mfma_k32(H, q_hi[dc], hh);
        lh = mfma_k32(L, q_hi[dc], lh);
        hl = mfma_k32(H, q_lo[dc], hl);
    }
}

// ---------------------------------------------------------------------------
// K0: pre-pack. blocks 0..1023: K -> khl rows [128 hi u16 | 128 lo u16].
// blocks 1024..2047: V -> vp u32 B-fragment pairs:
//   vp[(( (b*128+t)*4 + quad )*128 + n)*2 + w] = pack(V[t16+q4+2w][n], V[..+2w+1][n])
// ---------------------------------------------------------------------------
__global__ __launch_bounds__(256) void k0_pack(const float* __restrict__ key,
                                               const float* __restrict__ val,
                                               unsigned int* __restrict__ khl,
                                               unsigned int* __restrict__ vp) {
    const int tid = threadIdx.x;
    if (blockIdx.x < 1024) {
        int i = blockIdx.x * 256 + tid;          // one thread = 8 floats
        int row = i >> 4, seg = i & 15;
        const float* src = key + (size_t)row * D_ + seg * 8;
        float4 v0 = *(const float4*)src;
        float4 v1 = *(const float4*)(src + 4);
        uint2 h0, l0, h1, l1;
        split4(v0, h0, l0); split4(v1, h1, l1);
        unsigned int* dst = khl + (size_t)row * 128;
        *(uint4*)(dst + seg * 4)      = make_uint4(h0.x, h0.y, h1.x, h1.y);
        *(uint4*)(dst + 64 + seg * 4) = make_uint4(l0.x, l0.y, l1.x, l1.y);
    } else {
        int bt = blockIdx.x - 1024;              // b*128 + t (16-k tile)
        int kp = tid >> 5, n4 = tid & 31;        // kp: k-pair 0..7, n4: col/4
        int quad = kp >> 1, w = kp & 1;
        size_t r0 = ((size_t)bt * 16 + kp * 2) * D_;
        float4 a  = *(const float4*)(val + r0 + n4 * 4);
        float4 b4 = *(const float4*)(val + r0 + D_ + n4 * 4);
        unsigned int* q = vp + (((size_t)bt * 4 + quad) * 128 + n4 * 4) * 2 + w;
        q[0] = bfpack(a.x, b4.x);
        q[2] = bfpack(a.y, b4.y);
        q[4] = bfpack(a.z, b4.z);
        q[6] = bfpack(a.w, b4.w);
    }
}

// ---------------------------------------------------------------------------
// K1: qw = Q @ W, output packed hi/lo bf16 rows: [row][128 hi u16 | 128 lo u16]
// (512 B/row, aliases the `out` region).
// ---------------------------------------------------------------------------
__global__ __launch_bounds__(256) void k1_qw(const float* __restrict__ q,
                                             const float* __restrict__ w,
                                             unsigned int* __restrict__ qwp) {
    __shared__ float Ws[D_ * D_];
    const int tid = threadIdx.x;
    const int rowbase = blockIdx.x * 64;
    #pragma unroll
    for (int t = 0; t < 16; ++t) {
        int i4 = t * 256 + tid;
        ((float4*)Ws)[i4] = ((const float4*)w)[i4];
    }
    __syncthreads();
    const int mg = tid >> 4, cg = tid & 15;
    const int c0 = cg * 8;
    const float* qrow[4];
    #pragma unroll
    for (int i = 0; i < 4; ++i)
        qrow[i] = q + (size_t)(rowbase + mg * 4 + i) * D_;
    float acc[4][8];
    #pragma unroll
    for (int i = 0; i < 4; ++i)
        #pragma unroll
        for (int j = 0; j < 8; ++j) acc[i][j] = 0.0f;
    for (int d0 = 0; d0 < D_; d0 += 16) {
        float qr[4][16];
        #pragma unroll
        for (int i = 0; i < 4; ++i)
            #pragma unroll
            for (int c4 = 0; c4 < 4; ++c4)
                *(float4*)&qr[i][c4 * 4] = *(const float4*)(qrow[i] + d0 + c4 * 4);
        #pragma unroll
        for (int dd = 0; dd < 16; ++dd) {
            const int d = d0 + dd;
            float4 w0 = *(const float4*)&Ws[d * D_ + c0];
            float4 w1 = *(const float4*)&Ws[d * D_ + c0 + 4];
            #pragma unroll
            for (int i = 0; i < 4; ++i) {
                float a = qr[i][dd];
                acc[i][0] += a * w0.x; acc[i][1] += a * w0.y;
                acc[i][2] += a * w0.z; acc[i][3] += a * w0.w;
                acc[i][4] += a * w1.x; acc[i][5] += a * w1.y;
                acc[i][6] += a * w1.z; acc[i][7] += a * w1.w;
            }
        }
    }
    #pragma unroll
    for (int i = 0; i < 4; ++i) {
        float4 v0 = make_float4(acc[i][0], acc[i][1], acc[i][2], acc[i][3]);
        float4 v1 = make_float4(acc[i][4], acc[i][5], acc[i][6], acc[i][7]);
        uint2 h0, l0, h1, l1;
        split4(v0, h0, l0); split4(v1, h1, l1);
        unsigned int* dst = qwp + (size_t)(rowbase + mg * 4 + i) * 128;
        *(uint4*)(dst + cg * 4)      = make_uint4(h0.x, h0.y, h1.x, h1.y);
        *(uint4*)(dst + 64 + cg * 4) = make_uint4(l0.x, l0.y, l1.x, l1.y);
    }
}

// ---------------------------------------------------------------------------
// K_stats: per-row (max, sumexp) partials by recomputing S^T from packed K.
// wave = 16 q-rows x 512 k (one of 4 k-splits). No LDS, no barriers.
// ---------------------------------------------------------------------------
__global__ __launch_bounds__(256, 4) void k_stats(
        const unsigned short* __restrict__ qwp,
        const unsigned short* __restrict__ khl,
        float* __restrict__ mp, float* __restrict__ lp) {
    const int blk  = ((int)blockIdx.x & 7) * 128 + ((int)blockIdx.x >> 3);
    const int wid  = blk * 4 + (threadIdx.x >> 6);
    const int lane = threadIdx.x & 63;
    const int quad = lane >> 4, l15 = lane & 15;
    const int qb = wid & 127;
    const int ks = (wid >> 7) & 3;
    const int b  = wid >> 9;

    const unsigned short* qrow = qwp + ((size_t)b * SQ_ + qb * 16 + l15) * 256;
    s16x8 q_hi[4], q_lo[4];
    #pragma unroll
    for (int dc = 0; dc < 4; ++dc) {
        q_hi[dc] = *(const s16x8*)(qrow + dc * 32 + quad * 8);
        q_lo[dc] = *(const s16x8*)(qrow + 128 + dc * 32 + quad * 8);
    }

    const unsigned short* Kb = khl + ((size_t)b * SK_ + ks * KRANGE_) * 256;
    float m_run = -3.0e38f, l_run = 0.f;
    for (int st = 0; st < NSTEP_; ++st) {
        const unsigned short* kr = Kb + (size_t)(st * 16 + l15) * 256;
        f32x4 hh = (f32x4){0.f, 0.f, 0.f, 0.f};
        f32x4 lh = (f32x4){0.f, 0.f, 0.f, 0.f};
        f32x4 hl = (f32x4){0.f, 0.f, 0.f, 0.f};
        qk3(kr, q_hi, q_lo, quad, hh, lh, hl);
        f32x4 s4 = (hh + lh) + hl;
        float t = fmaxf(fmaxf(s4[0], s4[1]), fmaxf(s4[2], s4[3]));
        float mn = fmaxf(m_run, t);
        l_run = l_run * __expf(m_run - mn)
              + __expf(s4[0] - mn) + __expf(s4[1] - mn)
              + __expf(s4[2] - mn) + __expf(s4[3] - mn);
        m_run = mn;
    }
    #pragma unroll
    for (int off = 16; off <= 32; off <<= 1) {
        float om = __shfl_xor(m_run, off, 64);
        float ol = __shfl_xor(l_run, off, 64);
        float mn = fmaxf(m_run, om);
        l_run = l_run * __expf(m_run - mn) + ol * __expf(om - mn);
        m_run = mn;
    }
    if (lane < 16) {
        size_t row = (size_t)b * SQ_ + qb * 16 + l15;
        mp[(size_t)ks * BSQ_ + row] = m_run;
        lp[(size_t)ks * BSQ_ + row] = l_run;
    }
}

// ---------------------------------------------------------------------------
// K_fused: recompute S^T (bit-identical qk3), normalize, write weight once,
// PV via mfma 16x16x16 with pre-packed V fragments. LDS only for the final
// 4-way k-split O reduction. block = 512 thr = 2 q-groups x 4 k-splits.
// ---------------------------------------------------------------------------
__global__ __launch_bounds__(512, 2) void k_fused(
        const unsigned short* qwp,
        const unsigned short* __restrict__ khl,
        const uint2* __restrict__ vp,
        float* out, float* __restrict__ wgt,
        const float* __restrict__ mp, const float* __restrict__ lp) {
    __shared__ float Ot[32][132];
    const int tid  = threadIdx.x;
    const int blk  = ((int)blockIdx.x & 7) * 64 + ((int)blockIdx.x >> 3);
    const int wv   = tid >> 6;
    const int qg   = wv >> 2;        // q-group within block
    const int ks   = wv & 3;         // k-split
    const int lane = tid & 63, quad = lane >> 4, l15 = lane & 15;
    const int b  = blk >> 6;
    const int qb = (blk & 63) * 2 + qg;   // 16-row q group index (0..127)

    for (int i = tid; i < 32 * 132; i += 512) ((float*)Ot)[i] = 0.f;
    __syncthreads();

    const unsigned short* qrow = qwp + ((size_t)b * SQ_ + qb * 16 + l15) * 256;
    s16x8 q_hi[4], q_lo[4];
    #pragma unroll
    for (int dc = 0; dc < 4; ++dc) {
        q_hi[dc] = *(const s16x8*)(qrow + dc * 32 + quad * 8);
        q_lo[dc] = *(const s16x8*)(qrow + 128 + dc * 32 + quad * 8);
    }

    const size_t row = (size_t)b * SQ_ + qb * 16 + l15;
    float mf = -3.0e38f, lf = 0.f;
    #pragma unroll
    for (int s = 0; s < KSPLIT_; ++s) {
        float ms = mp[(size_t)s * BSQ_ + row];
        float ls = lp[(size_t)s * BSQ_ + row];
        float mn = fmaxf(mf, ms);
        lf = lf * __expf(mf - mn) + ls * __expf(ms - mn);
        mf = mn;
    }
    const float linv = 1.0f / lf;

    const unsigned short* Kb = khl + ((size_t)b * SK_ + ks * KRANGE_) * 256;
    const uint2* Vb = vp + (((size_t)(b * 128 + ks * 32) * 4 + quad) * 128 + l15);
    float* Wp = wgt + row * SK_ + ks * KRANGE_ + quad * 4;

    f32x4 acc_o[8];
    #pragma unroll
    for (int i = 0; i < 8; ++i) acc_o[i] = (f32x4){0.f, 0.f, 0.f, 0.f};

    for (int st = 0; st < NSTEP_; ++st) {
        // prefetch this step's V fragments (independent of the QK chain)
        uint2 vfr[8];
        #pragma unroll
        for (int vt = 0; vt < 8; ++vt) vfr[vt] = Vb[(size_t)st * 512 + vt * 16];

        const unsigned short* kr = Kb + (size_t)(st * 16 + l15) * 256;
        f32x4 hh = (f32x4){0.f, 0.f, 0.f, 0.f};
        f32x4 lh = (f32x4){0.f, 0.f, 0.f, 0.f};
        f32x4 hl = (f32x4){0.f, 0.f, 0.f, 0.f};
        qk3(kr, q_hi, q_lo, quad, hh, lh, hl);    // identical to k_stats
        f32x4 s4 = (hh + lh) + hl;

        f32x4 p;
        #pragma unroll
        for (int r = 0; r < 4; ++r) p[r] = __expf(s4[r] - mf) * linv;
        *(float4*)(Wp + st * 16) = make_float4(p[0], p[1], p[2], p[3]);

        U4 A; A.u[0] = bfpack(p[0], p[1]); A.u[1] = bfpack(p[2], p[3]);
        #pragma unroll
        for (int vt = 0; vt < 8; ++vt) {
            U4 Bv; Bv.u[0] = vfr[vt].x; Bv.u[1] = vfr[vt].y;
            acc_o[vt] = mfma_k16(A.v, Bv.v, acc_o[vt]);
        }
    }

    // 4-way k-split reduction of O in LDS (one-time)
    #pragma unroll
    for (int vt = 0; vt < 8; ++vt)
        #pragma unroll
        for (int r = 0; r < 4; ++r)
            atomicAdd(&Ot[qg * 16 + quad * 4 + r][vt * 16 + l15], acc_o[vt][r]);
    __syncthreads();

    float* ob = out + ((size_t)b * SQ_ + (size_t)(blk & 63) * 32) * D_;
    for (int i = tid; i < 32 * 32; i += 512) {
        int r = i >> 5, c4 = i & 31;
        *(float4*)(ob + (size_t)r * D_ + c4 * 4) = *(const float4*)&Ot[r][c4 * 4];
    }
}

extern "C" void kernel_launch(void* const* d_in, const int* in_sizes, int n_in,
                              void* d_out, int out_size, void* d_ws, size_t ws_size,
                              hipStream_t stream) {
    const float* q = (const float*)d_in[0];
    const float* k = (const float*)d_in[1];
    const float* v = (const float*)d_in[2];
    const float* w = (const float*)d_in[3];
    float* out    = (float*)d_out;
    float* weight = out + (size_t)BSQ_ * D_;
    unsigned int* qwp = (unsigned int*)out;       // packed hi/lo bf16 qw, aliases out

    // workspace: khl 8MB | vp 4MB | mp 256KB | lp 256KB  (12.5MB total)
    unsigned int* khl = (unsigned int*)d_ws;
    unsigned int* vp  = khl + (size_t)BSQ_ * 128;            // +2M u32
    float* mp = (float*)(vp + (size_t)B_ * 128 * 4 * 128 * 2);
    float* lp = mp + (size_t)KSPLIT_ * BSQ_;

    k0_pack<<<2048, 256, 0, stream>>>(k, v, khl, vp);
    k1_qw  <<<BSQ_ / 64, 256, 0, stream>>>(q, w, qwp);
    k_stats<<<BSQ_ / 16, 256, 0, stream>>>((const unsigned short*)qwp,
                                           (const unsigned short*)khl, mp, lp);
    k_fused<<<BSQ_ / 32, 512, 0, stream>>>((const unsigned short*)qwp,
                                           (const unsigned short*)khl,
                                           (const uint2*)vp, out, weight, mp, lp);
}